// Round 9
// baseline (995.867 us; speedup 1.0000x reference)
//
#include <hip/hip_runtime.h>
#include <cstdint>
#include <cstddef>

// ---------------- helpers ----------------
typedef __attribute__((ext_vector_type(8))) short bf16x8;
typedef __attribute__((ext_vector_type(4))) float f32x4;
typedef __attribute__((ext_vector_type(8))) unsigned short u16x8;

__device__ __forceinline__ float lrelu02(float x) { return x > 0.f ? x : 0.2f * x; }
__device__ __forceinline__ unsigned short f2bf(float f) {
  unsigned u = __float_as_uint(f);
  unsigned r = u + 0x7FFFu + ((u >> 16) & 1u);  // RNE
  return (unsigned short)(r >> 16);
}
__device__ __forceinline__ float bf2f(unsigned short b) {
  return __uint_as_float(((unsigned)b) << 16);
}

__device__ __forceinline__ void gll16(const void* g, void* l) {
  __builtin_amdgcn_global_load_lds(
      (const __attribute__((address_space(1))) void*)g,
      (__attribute__((address_space(3))) void*)l, 16, 0, 0);
}

// ---------------- hist + weight-prep (merged) ----------------
// blocks [0,gE): histogram of dst; [gE,gE+1024): W1t; +128: W2t; last: cn + red init
__global__ void hist_prep_k(const int* __restrict__ ei, int E, int N,
                            int* __restrict__ counts, int gE,
                            const float* __restrict__ W1, unsigned short* __restrict__ W1t,
                            const float* __restrict__ W2, unsigned short* __restrict__ W2t,
                            const float* __restrict__ ca, float* __restrict__ cn,
                            unsigned* __restrict__ red) {
  const int b = blockIdx.x;
  const int tid = threadIdx.x;
  if (b < gE) {
    int i = b * 256 + tid;
    int Eall = E + N;
    if (i >= Eall) return;
    int dst = (i < E) ? ei[E + i] : (i - E);
    atomicAdd(&counts[dst], 1);
  } else {
    int bb = b - gE;
    if (bb < 1024) {
      int i = bb * 256 + tid;
      int c = i >> 9, k = i & 511;
      W1t[i] = f2bf(W1[(size_t)k * 512 + c]);
    } else if (bb < 1024 + 128) {
      int i = (bb - 1024) * 256 + tid;
      int c = i >> 9, k = i & 511;
      W2t[i] = f2bf(W2[(size_t)k * 64 + c]);
    } else {
      int lane = tid & 63, c = tid >> 6;
      float v = ca[c * 64 + lane];
      float p = v * v;
#pragma unroll
      for (int o = 32; o; o >>= 1) p += __shfl_xor(p, o);
      cn[c * 64 + lane] = v / fmaxf(sqrtf(p), 1e-12f);
      if (tid == 0) { red[0] = 0u; red[1] = 0u; }
    }
  }
}

// ---------------- scan phase 1: per-256-chunk inclusive scan + chunk sums ----------------
__global__ __launch_bounds__(256) void scan1_k(const int* __restrict__ counts,
                                               int* __restrict__ incl,
                                               int* __restrict__ bsum, int N) {
  int b = blockIdx.x, tid = threadIdx.x;
  int lane = tid & 63, wv = tid >> 6;
  int i = b * 256 + tid;
  int v = (i < N) ? counts[i] : 0;
#pragma unroll
  for (int o = 1; o < 64; o <<= 1) {
    int t = __shfl_up(v, o, 64);
    if (lane >= o) v += t;
  }
  __shared__ int wsum[4];
  if (lane == 63) wsum[wv] = v;
  __syncthreads();
  int base = 0;
  for (int wj = 0; wj < wv; wj++) base += wsum[wj];
  v += base;
  if (i < N) incl[i] = v;
  if (tid == 255) bsum[b] = v;
}

// ---------------- scan phase 2 (inlined prefix) + emit offs/cursor ----------------
// block b reduces bsum[0..b-1] itself (nb <= ~256, trivial cost)
__global__ __launch_bounds__(256) void scan3_k(const int* __restrict__ incl,
                                               const int* __restrict__ bsum,
                                               int* __restrict__ offs,
                                               int* __restrict__ cursor, int N) {
  const int b = blockIdx.x, tid = threadIdx.x;
  __shared__ int s_pre;
  if (tid < 64) {
    int p = 0;
    for (int i = tid; i < b; i += 64) p += bsum[i];
#pragma unroll
    for (int o = 32; o; o >>= 1) p += __shfl_xor(p, o);
    if (tid == 0) s_pre = p;
  }
  __syncthreads();
  const int prefix = s_pre;
  int i = b * 256 + tid;
  if (i == 0) { offs[0] = 0; cursor[0] = 0; }
  if (i < N) {
    int v = incl[i] + prefix;
    offs[i + 1] = v;
    if (i + 1 < N) cursor[i + 1] = v;
  }
}

__global__ void scatter_k(const int* __restrict__ ei, int E, int N,
                          int* __restrict__ cursor, int* __restrict__ ssrc) {
  int i = blockIdx.x * 256 + threadIdx.x;
  int Eall = E + N;
  if (i >= Eall) return;
  int src, dst;
  if (i < E) { src = ei[i]; dst = ei[E + i]; }
  else       { src = i - E; dst = i - E; }
  int pos = atomicAdd(&cursor[dst], 1);
  ssrc[pos] = src;
}

// ---------------- GEMM1: h[M,512] = x_fp32[M,512] @ W1t^T, bf16 out, fused dots ----------------
// BM=128, BN=512 (single col-pass), BK=64; 1024 thr, 16 waves (2 row x 8 col),
// wave tile 64x64 (acc[4][4] -> ~110 VGPR -> 4 waves/SIMD). grid (Mpad/128).
// A staged from fp32 via reg-load + f2bf + ds_write (conv fused). LDS = 16+64+8 = 88 KB.
__global__ __launch_bounds__(1024, 1) void gemm1_k(const float* __restrict__ X,
                                                   const unsigned short* __restrict__ Bt,
                                                   unsigned short* __restrict__ C,
                                                   const float* __restrict__ att_s,
                                                   const float* __restrict__ att_d,
                                                   float* __restrict__ as_out,
                                                   float* __restrict__ ad_out,
                                                   int M, int K, int Nc) {
  __shared__ unsigned short As[128][64];
  __shared__ unsigned short Bs[512][64];
  __shared__ float s_ds[8][128];
  __shared__ float s_dd[8][128];
  const int tid = threadIdx.x;
  const int lane = tid & 63;
  const int w = tid >> 6;          // 0..15
  const int wr = w >> 3, wc = w & 7;
  const int l16 = lane & 15, lk = lane >> 4;
  const int row0 = blockIdx.x * 128;

  f32x4 acc[4][4];
#pragma unroll
  for (int m = 0; m < 4; m++)
#pragma unroll
    for (int n = 0; n < 4; n++) acc[m][n] = (f32x4)0.f;

  const char* Bbase = (const char*)Bt;

  for (int k0 = 0; k0 < K; k0 += 64) {
    // B tile: 512 rows x 128B = 4096 16B-chunks, 4 per thread
#pragma unroll
    for (int i = 0; i < 4; i++) {
      int cb = i * 1024 + tid;
      int c = cb >> 3, b = (cb & 7) * 16;
      gll16(Bbase + ((size_t)c * K + k0) * 2 + b, (char*)&Bs[0][0] + cb * 16);
    }
    // A tile: 128x64 fp32 -> bf16; 1024 octets, 1 per thread
    {
      int r = tid >> 3, c = (tid & 7) * 8;
      int row = row0 + r;
      if (row >= M) row = M - 1;
      const float* src = X + (size_t)row * K + k0 + c;
      float4 a0 = *(const float4*)src;
      float4 a1 = *(const float4*)(src + 4);
      u16x8 pk;
      pk[0] = f2bf(a0.x); pk[1] = f2bf(a0.y); pk[2] = f2bf(a0.z); pk[3] = f2bf(a0.w);
      pk[4] = f2bf(a1.x); pk[5] = f2bf(a1.y); pk[6] = f2bf(a1.z); pk[7] = f2bf(a1.w);
      *(u16x8*)&As[r][c] = pk;
    }
    __syncthreads();
#pragma unroll
    for (int ks = 0; ks < 2; ks++) {
      bf16x8 af[4], bfr[4];
#pragma unroll
      for (int m = 0; m < 4; m++)
        af[m] = *(const bf16x8*)&As[wr * 64 + m * 16 + l16][ks * 32 + lk * 8];
#pragma unroll
      for (int n = 0; n < 4; n++)
        bfr[n] = *(const bf16x8*)&Bs[wc * 64 + n * 16 + l16][ks * 32 + lk * 8];
#pragma unroll
      for (int m = 0; m < 4; m++)
#pragma unroll
        for (int n = 0; n < 4; n++)
          acc[m][n] = __builtin_amdgcn_mfma_f32_16x16x32_bf16(af[m], bfr[n], acc[m][n], 0, 0, 0);
    }
    __syncthreads();
  }
  // C write (bf16); C/D layout col=lane&15, row=(lane>>4)*4+reg
#pragma unroll
  for (int m = 0; m < 4; m++) {
    int row_b = row0 + wr * 64 + m * 16 + lk * 4;
#pragma unroll
    for (int r = 0; r < 4; r++) {
      int row = row_b + r;
      if (row < M) {
#pragma unroll
        for (int n = 0; n < 4; n++) {
          int col = wc * 64 + n * 16 + l16;
          C[(size_t)row * Nc + col] = f2bf(acc[m][n][r]);
        }
      }
    }
  }
  // fused dots: head = wc>>1 (two waves per head, combined in LDS)
  float as_c[4], ad_c[4];
#pragma unroll
  for (int n = 0; n < 4; n++) {
    int col = wc * 64 + n * 16 + l16;
    as_c[n] = att_s[col];
    ad_c[n] = att_d[col];
  }
#pragma unroll
  for (int m = 0; m < 4; m++) {
#pragma unroll
    for (int r = 0; r < 4; r++) {
      float ps = 0.f, pd = 0.f;
#pragma unroll
      for (int n = 0; n < 4; n++) {
        ps += acc[m][n][r] * as_c[n];
        pd += acc[m][n][r] * ad_c[n];
      }
#pragma unroll
      for (int o = 8; o; o >>= 1) { ps += __shfl_xor(ps, o); pd += __shfl_xor(pd, o); }
      if (l16 == 0) {
        int rr = wr * 64 + m * 16 + lk * 4 + r;
        s_ds[wc][rr] = ps;
        s_dd[wc][rr] = pd;
      }
    }
  }
  __syncthreads();
  if (tid < 128) {
    int row = row0 + tid;
    if (row < M) {
#pragma unroll
      for (int h = 0; h < 4; h++) {
        as_out[(size_t)row * 4 + h] = s_ds[2 * h][tid] + s_ds[2 * h + 1][tid];
        ad_out[(size_t)row * 4 + h] = s_dd[2 * h][tid] + s_dd[2 * h + 1][tid];
      }
    }
  }
}

// ---------------- GEMM2: h2pre[M,64] = h1b[M,512] @ W2t^T, bf16 out, fused dots ----------------
__global__ __launch_bounds__(256) void gemm2_k(const unsigned short* __restrict__ A,
                                               const unsigned short* __restrict__ Bt,
                                               unsigned short* __restrict__ C,
                                               const float* __restrict__ att_s,
                                               const float* __restrict__ att_d,
                                               float* __restrict__ as_out,
                                               float* __restrict__ ad_out,
                                               int M, int K, int Nc) {
  __shared__ unsigned short As[64][64];
  __shared__ unsigned short Bs[64][64];
  __shared__ float s_ds[2][64];
  __shared__ float s_dd[2][64];
  const int tid = threadIdx.x;
  const int lane = tid & 63;
  const int w = tid >> 6;
  const int wr = w >> 1, wc = w & 1;
  const int l16 = lane & 15, lk = lane >> 4;
  const int row0 = blockIdx.x * 64;

  f32x4 acc[2][2];
#pragma unroll
  for (int m = 0; m < 2; m++)
#pragma unroll
    for (int n = 0; n < 2; n++) acc[m][n] = (f32x4)0.f;

  const char* Abase = (const char*)A;
  const char* Bbase = (const char*)Bt;

  for (int k0 = 0; k0 < K; k0 += 64) {
#pragma unroll
    for (int i = 0; i < 2; i++) {
      int ca = i * 256 + tid;
      int r = ca >> 3, b = (ca & 7) * 16;
      gll16(Abase + ((size_t)(row0 + r) * K + k0) * 2 + b, (char*)&As[0][0] + ca * 16);
    }
#pragma unroll
    for (int i = 0; i < 2; i++) {
      int cb = i * 256 + tid;
      int c = cb >> 3, b = (cb & 7) * 16;
      gll16(Bbase + ((size_t)c * K + k0) * 2 + b, (char*)&Bs[0][0] + cb * 16);
    }
    __syncthreads();
#pragma unroll
    for (int ks = 0; ks < 2; ks++) {
      bf16x8 af[2], bfr[2];
#pragma unroll
      for (int m = 0; m < 2; m++)
        af[m] = *(const bf16x8*)&As[wr * 32 + m * 16 + l16][ks * 32 + lk * 8];
#pragma unroll
      for (int n = 0; n < 2; n++)
        bfr[n] = *(const bf16x8*)&Bs[wc * 32 + n * 16 + l16][ks * 32 + lk * 8];
#pragma unroll
      for (int m = 0; m < 2; m++)
#pragma unroll
        for (int n = 0; n < 2; n++)
          acc[m][n] = __builtin_amdgcn_mfma_f32_16x16x32_bf16(af[m], bfr[n], acc[m][n], 0, 0, 0);
    }
    __syncthreads();
  }
#pragma unroll
  for (int m = 0; m < 2; m++) {
    int row_b = row0 + wr * 32 + m * 16 + lk * 4;
#pragma unroll
    for (int r = 0; r < 4; r++) {
      int row = row_b + r;
      if (row < M) {
#pragma unroll
        for (int n = 0; n < 2; n++) {
          int col = wc * 32 + n * 16 + l16;
          C[(size_t)row * Nc + col] = f2bf(acc[m][n][r]);
        }
      }
    }
  }
  float as_c[2], ad_c[2];
#pragma unroll
  for (int n = 0; n < 2; n++) {
    int col = wc * 32 + n * 16 + l16;
    as_c[n] = att_s[col];
    ad_c[n] = att_d[col];
  }
#pragma unroll
  for (int m = 0; m < 2; m++) {
#pragma unroll
    for (int r = 0; r < 4; r++) {
      float ps = 0.f, pd = 0.f;
#pragma unroll
      for (int n = 0; n < 2; n++) {
        ps += acc[m][n][r] * as_c[n];
        pd += acc[m][n][r] * ad_c[n];
      }
#pragma unroll
      for (int o = 8; o; o >>= 1) { ps += __shfl_xor(ps, o); pd += __shfl_xor(pd, o); }
      if (l16 == 0) {
        int rr = wr * 32 + m * 16 + lk * 4 + r;
        s_ds[wc][rr] = ps;
        s_dd[wc][rr] = pd;
      }
    }
  }
  __syncthreads();
  if (tid < 64) {
    int row = row0 + tid;
    if (row < M) {
      as_out[row] = s_ds[0][tid] + s_ds[1][tid];
      ad_out[row] = s_dd[0][tid] + s_dd[1][tid];
    }
  }
}

// ---------------- GAT layer 1 aggregation: wave per dst node, barrier-free ----------------
__global__ __launch_bounds__(256) void gat_agg1_k(const unsigned short* __restrict__ hfeat,
                                                  const float* __restrict__ a_s,
                                                  const float* __restrict__ a_d,
                                                  const int* __restrict__ offs,
                                                  const int* __restrict__ ssrc,
                                                  const float* __restrict__ b1,
                                                  unsigned short* __restrict__ h1b, int N) {
  const int tid = threadIdx.x;
  const int lane = tid & 63, wave = tid >> 6;
  const int n = blockIdx.x * 4 + wave;
  if (n >= N) return;
  __shared__ int   s_src[4][64];
  __shared__ float s_ex[4][64][4];
  const int start = offs[n], end = offs[n + 1];
  const int hhl = lane >> 4;
  const float4 adv4 = *(const float4*)(a_d + (size_t)n * 4);
  const float4* as4 = (const float4*)a_s;

  float m0 = -1e30f, m1 = -1e30f, m2 = -1e30f, m3 = -1e30f;
  float S0 = 0.f, S1 = 0.f, S2 = 0.f, S3 = 0.f;
  float acc[8] = {0.f, 0.f, 0.f, 0.f, 0.f, 0.f, 0.f, 0.f};

  for (int base = start; base < end; base += 64) {
    const int cnt = min(64, end - base);
    float e0 = -1e30f, e1 = -1e30f, e2 = -1e30f, e3 = -1e30f;
    int s = 0;
    if (lane < cnt) {
      s = ssrc[base + lane];
      float4 av = as4[s];
      e0 = lrelu02(av.x + adv4.x);
      e1 = lrelu02(av.y + adv4.y);
      e2 = lrelu02(av.z + adv4.z);
      e3 = lrelu02(av.w + adv4.w);
    }
    float c0 = e0, c1 = e1, c2 = e2, c3 = e3;
#pragma unroll
    for (int o = 32; o; o >>= 1) {
      c0 = fmaxf(c0, __shfl_xor(c0, o));
      c1 = fmaxf(c1, __shfl_xor(c1, o));
      c2 = fmaxf(c2, __shfl_xor(c2, o));
      c3 = fmaxf(c3, __shfl_xor(c3, o));
    }
    float nm0 = fmaxf(m0, c0), nm1 = fmaxf(m1, c1);
    float nm2 = fmaxf(m2, c2), nm3 = fmaxf(m3, c3);
    float sc0 = __expf(m0 - nm0), sc1 = __expf(m1 - nm1);
    float sc2 = __expf(m2 - nm2), sc3 = __expf(m3 - nm3);
    m0 = nm0; m1 = nm1; m2 = nm2; m3 = nm3;
    float x0 = (lane < cnt) ? __expf(e0 - nm0) : 0.f;
    float x1 = (lane < cnt) ? __expf(e1 - nm1) : 0.f;
    float x2 = (lane < cnt) ? __expf(e2 - nm2) : 0.f;
    float x3 = (lane < cnt) ? __expf(e3 - nm3) : 0.f;
    s_src[wave][lane] = s;
    s_ex[wave][lane][0] = x0; s_ex[wave][lane][1] = x1;
    s_ex[wave][lane][2] = x2; s_ex[wave][lane][3] = x3;
#pragma unroll
    for (int o = 32; o; o >>= 1) {
      x0 += __shfl_xor(x0, o); x1 += __shfl_xor(x1, o);
      x2 += __shfl_xor(x2, o); x3 += __shfl_xor(x3, o);
    }
    S0 = S0 * sc0 + x0; S1 = S1 * sc1 + x1;
    S2 = S2 * sc2 + x2; S3 = S3 * sc3 + x3;
    float scl = (hhl == 0) ? sc0 : (hhl == 1) ? sc1 : (hhl == 2) ? sc2 : sc3;
#pragma unroll
    for (int q = 0; q < 8; q++) acc[q] *= scl;
#pragma unroll 4
    for (int j = 0; j < cnt; j++) {
      int sj = s_src[wave][j];
      float al = s_ex[wave][j][hhl];
      uint4 pk = *(const uint4*)(hfeat + ((size_t)sj << 9) + lane * 8);
      acc[0] += al * __uint_as_float(pk.x << 16);
      acc[1] += al * __uint_as_float(pk.x & 0xFFFF0000u);
      acc[2] += al * __uint_as_float(pk.y << 16);
      acc[3] += al * __uint_as_float(pk.y & 0xFFFF0000u);
      acc[4] += al * __uint_as_float(pk.z << 16);
      acc[5] += al * __uint_as_float(pk.z & 0xFFFF0000u);
      acc[6] += al * __uint_as_float(pk.w << 16);
      acc[7] += al * __uint_as_float(pk.w & 0xFFFF0000u);
    }
  }
  float inv = 1.f / (((hhl == 0) ? S0 : (hhl == 1) ? S1 : (hhl == 2) ? S2 : S3) + 1e-16f);
  const float4 b1a = *(const float4*)(b1 + lane * 8);
  const float4 b1b = *(const float4*)(b1 + lane * 8 + 4);
  float v[8];
  v[0] = acc[0] * inv + b1a.x; v[1] = acc[1] * inv + b1a.y;
  v[2] = acc[2] * inv + b1a.z; v[3] = acc[3] * inv + b1a.w;
  v[4] = acc[4] * inv + b1b.x; v[5] = acc[5] * inv + b1b.y;
  v[6] = acc[6] * inv + b1b.z; v[7] = acc[7] * inv + b1b.w;
  u16x8 outv;
#pragma unroll
  for (int q = 0; q < 8; q++) {
    float t = v[q] > 0.f ? v[q] : (__expf(v[q]) - 1.f);
    outv[q] = f2bf(t);
  }
  __builtin_nontemporal_store(outv, (u16x8*)(h1b + ((size_t)n << 9) + lane * 8));
}

// ---------------- GAT layer 2 aggregation + fused score + fused exp-sum ----------------
__global__ __launch_bounds__(256) void gat_agg2_k(const unsigned short* __restrict__ h2b,
                                                  const float* __restrict__ a_s,
                                                  const float* __restrict__ a_d,
                                                  const int* __restrict__ offs,
                                                  const int* __restrict__ ssrc,
                                                  const float* __restrict__ b2,
                                                  const float* __restrict__ Wa,
                                                  const float* __restrict__ ba,
                                                  const float* __restrict__ wv,
                                                  const float* __restrict__ bv,
                                                  float* __restrict__ h2out,
                                                  float* __restrict__ scores,
                                                  unsigned* __restrict__ red, int N) {
  const int tid = threadIdx.x;
  const int lane = tid & 63, wave = tid >> 6;
  const int n = blockIdx.x * 4 + wave;
  if (n >= N) return;
  __shared__ int   s_src[4][64];
  __shared__ float s_ex[4][64];
  const int start = offs[n], end = offs[n + 1];
  const float ad = a_d[n];
  const int half = lane >> 5, l32 = lane & 31;

  float m = -1e30f, S = 0.f, acc0 = 0.f, acc1 = 0.f;
  for (int base = start; base < end; base += 64) {
    const int cnt = min(64, end - base);
    float e = -1e30f;
    int s = 0;
    if (lane < cnt) {
      s = ssrc[base + lane];
      e = lrelu02(a_s[s] + ad);
    }
    float c = e;
#pragma unroll
    for (int o = 32; o; o >>= 1) c = fmaxf(c, __shfl_xor(c, o));
    float nm = fmaxf(m, c);
    float sc = __expf(m - nm);
    m = nm;
    float x = (lane < cnt) ? __expf(e - nm) : 0.f;
    s_src[wave][lane] = s;
    s_ex[wave][lane] = x;
    float xs = x;
#pragma unroll
    for (int o = 32; o; o >>= 1) xs += __shfl_xor(xs, o);
    S = S * sc + xs;
    acc0 *= sc; acc1 *= sc;
#pragma unroll 8
    for (int j = half; j < cnt; j += 2) {
      int sj = s_src[wave][j];
      float al = s_ex[wave][j];
      unsigned pk = *(const unsigned*)(h2b + ((size_t)sj << 6) + l32 * 2);
      acc0 += al * __uint_as_float(pk << 16);
      acc1 += al * __uint_as_float(pk & 0xFFFF0000u);
    }
  }
  acc0 += __shfl_xor(acc0, 32);
  acc1 += __shfl_xor(acc1, 32);
  float inv = 1.f / (S + 1e-16f);
  float hx = acc0 * inv + b2[l32 * 2];
  float hy = acc1 * inv + b2[l32 * 2 + 1];
  if (half == 0) {
    float2 o;
    o.x = hx; o.y = hy;
    *(float2*)(h2out + ((size_t)n << 6) + l32 * 2) = o;
  }
  // fused score: t[lane] = ba[lane] + sum_k h2[k]*Wa[k][lane]
  float t = ba[lane];
#pragma unroll 8
  for (int k = 0; k < 32; k++) {
    float a = __shfl(hx, k);
    float b = __shfl(hy, k);
    t += a * Wa[(2 * k) * 64 + lane] + b * Wa[(2 * k + 1) * 64 + lane];
  }
  t = tanhf(t);
  float p = t * wv[lane];
#pragma unroll
  for (int o = 32; o; o >>= 1) p += __shfl_xor(p, o);
  if (lane == 0) {
    float sc = p + bv[0];
    scores[n] = sc;
    // scores tanh-bounded -> no max-shift needed for the global softmax
    atomicAdd(reinterpret_cast<float*>(red) + 1, __expf(sc));
  }
}

__global__ __launch_bounds__(256) void finalize_k(const float* __restrict__ h2,
                                                  const float* __restrict__ scores,
                                                  const unsigned* __restrict__ red,
                                                  const float* __restrict__ cn,
                                                  const float* __restrict__ Wc,
                                                  const float* __restrict__ bc,
                                                  float* __restrict__ out, int N) {
  int lane = threadIdx.x & 63, wave = threadIdx.x >> 6;
  int n = blockIdx.x * 4 + wave;
  if (n >= N) return;
  float S = __uint_as_float(red[1]);
  float attw = __expf(scores[n]) / S;
  float xw = h2[(size_t)n * 64 + lane] * attw;
  float p = xw * xw;
#pragma unroll
  for (int o = 32; o; o >>= 1) p += __shfl_xor(p, o);
  float xn = xw / fmaxf(sqrtf(p), 1e-12f);
  float i0 = xn * cn[lane],       i1 = xn * cn[64 + lane];
  float i2 = xn * cn[128 + lane], i3 = xn * cn[192 + lane];
  float o0 = xw * Wc[lane * 4 + 0], o1 = xw * Wc[lane * 4 + 1];
  float o2 = xw * Wc[lane * 4 + 2], o3 = xw * Wc[lane * 4 + 3];
#pragma unroll
  for (int o = 32; o; o >>= 1) {
    i0 += __shfl_xor(i0, o); i1 += __shfl_xor(i1, o);
    i2 += __shfl_xor(i2, o); i3 += __shfl_xor(i3, o);
    o0 += __shfl_xor(o0, o); o1 += __shfl_xor(o1, o);
    o2 += __shfl_xor(o2, o); o3 += __shfl_xor(o3, o);
  }
  float* outp   = out;
  float* xwp    = out + (size_t)N * 4;
  float* interp = out + (size_t)N * 68;
  xwp[(size_t)n * 64 + lane] = xw;
  if (lane == 0) {
    outp[n * 4 + 0] = o0 + bc[0]; outp[n * 4 + 1] = o1 + bc[1];
    outp[n * 4 + 2] = o2 + bc[2]; outp[n * 4 + 3] = o3 + bc[3];
    interp[n * 4 + 0] = i0; interp[n * 4 + 1] = i1;
    interp[n * 4 + 2] = i2; interp[n * 4 + 3] = i3;
  }
}

// ---------------- launch ----------------
extern "C" void kernel_launch(void* const* d_in, const int* in_sizes, int n_in,
                              void* d_out, int out_size, void* d_ws, size_t ws_size,
                              hipStream_t stream) {
  const float* x        = (const float*)d_in[0];
  const int*   ei       = (const int*)d_in[1];
  const float* W1       = (const float*)d_in[2];
  const float* att_src1 = (const float*)d_in[3];
  const float* att_dst1 = (const float*)d_in[4];
  const float* b1       = (const float*)d_in[5];
  const float* W2       = (const float*)d_in[6];
  const float* att_src2 = (const float*)d_in[7];
  const float* att_dst2 = (const float*)d_in[8];
  const float* b2       = (const float*)d_in[9];
  const float* Wa       = (const float*)d_in[10];
  const float* ba       = (const float*)d_in[11];
  const float* wv       = (const float*)d_in[12];
  const float* bv       = (const float*)d_in[13];
  const float* class_attn = (const float*)d_in[14];
  const float* Wc       = (const float*)d_in[15];
  const float* bc       = (const float*)d_in[16];

  const int N = in_sizes[0] / 512;
  const int E = in_sizes[1] / 2;
  const int Eall = E + N;
  const int Mpad = ((N + 127) / 128) * 128;
  const int nb = (N + 255) / 256;

  char* w = (char*)d_ws;
  size_t off = 0;
  auto alloc = [&](size_t bytes) -> void* {
    off = (off + 255) & ~((size_t)255);
    void* p = w + off;
    off += bytes;
    return p;
  };
  unsigned short* h1b = (unsigned short*)alloc((size_t)Mpad * 512 * 2);
  unsigned short* hb  = (unsigned short*)alloc((size_t)N * 512 * 2);     // h = x@W1, bf16
  unsigned short* h2b = (unsigned short*)alloc((size_t)N * 64 * 2);      // h2pre bf16
  float* h2     = (float*)alloc((size_t)N * 64 * 4);
  unsigned short* W1t = (unsigned short*)alloc((size_t)512 * 512 * 2);
  unsigned short* W2t = (unsigned short*)alloc((size_t)64 * 512 * 2);
  float* as1    = (float*)alloc((size_t)N * 4 * 4);
  float* ad1    = (float*)alloc((size_t)N * 4 * 4);
  float* as2    = (float*)alloc((size_t)N * 4);
  float* ad2    = (float*)alloc((size_t)N * 4);
  int*   counts = (int*)alloc((size_t)N * 4);
  int*   incl   = (int*)alloc((size_t)N * 4);
  int*   bsum   = (int*)alloc(256 * 4);
  int*   offs   = (int*)alloc((size_t)(N + 1) * 4);
  int*   cursor = (int*)alloc((size_t)N * 4);
  int*   ssrc   = (int*)alloc((size_t)Eall * 4);
  float* scores = (float*)alloc((size_t)N * 4);
  unsigned* red = (unsigned*)alloc(64);
  float* cn     = (float*)alloc(256 * 4);

  const int gN256  = (N + 255) / 256;
  const int gE256  = (Eall + 255) / 256;
  const int gNode4 = (N + 3) / 4;

  // --- CSR build + weight prep ---
  hipMemsetAsync(counts, 0, (size_t)N * 4, stream);
  hist_prep_k<<<gE256 + 1024 + 128 + 1, 256, 0, stream>>>(
      ei, E, N, counts, gE256, W1, W1t, W2, W2t, class_attn, cn, red);
  scan1_k<<<nb, 256, 0, stream>>>(counts, incl, bsum, N);
  scan3_k<<<gN256, 256, 0, stream>>>(incl, bsum, offs, cursor, N);
  scatter_k<<<gE256, 256, 0, stream>>>(ei, E, N, cursor, ssrc);

  // --- layer 1 ---
  gemm1_k<<<Mpad / 128, 1024, 0, stream>>>(
      x, W1t, hb, att_src1, att_dst1, as1, ad1, N, 512, 512);
  gat_agg1_k<<<gNode4, 256, 0, stream>>>(hb, as1, ad1, offs, ssrc, b1, h1b, N);

  // --- layer 2 ---
  gemm2_k<<<dim3(Mpad / 64, 1), 256, 0, stream>>>(
      h1b, W2t, h2b, att_src2, att_dst2, as2, ad2, N, 512, 64);
  gat_agg2_k<<<gNode4, 256, 0, stream>>>(h2b, as2, ad2, offs, ssrc, b2,
                                         Wa, ba, wv, bv, h2, scores, red, N);

  // --- finalize (reads global exp-sum computed in agg2) ---
  finalize_k<<<gNode4, 256, 0, stream>>>(h2, scores, red, cn, Wc, bc,
                                         (float*)d_out, N);
}

// Round 10
// 418.298 us; speedup vs baseline: 2.3808x; 2.3808x over previous
//
#include <hip/hip_runtime.h>
#include <cstdint>
#include <cstddef>

// ---------------- helpers ----------------
typedef __attribute__((ext_vector_type(8))) short bf16x8;
typedef __attribute__((ext_vector_type(4))) float f32x4;
typedef __attribute__((ext_vector_type(8))) unsigned short u16x8;

__device__ __forceinline__ float lrelu02(float x) { return x > 0.f ? x : 0.2f * x; }
__device__ __forceinline__ unsigned short f2bf(float f) {
  unsigned u = __float_as_uint(f);
  unsigned r = u + 0x7FFFu + ((u >> 16) & 1u);  // RNE
  return (unsigned short)(r >> 16);
}
__device__ __forceinline__ float bf2f(unsigned short b) {
  return __uint_as_float(((unsigned)b) << 16);
}

__device__ __forceinline__ void gll16(const void* g, void* l) {
  __builtin_amdgcn_global_load_lds(
      (const __attribute__((address_space(1))) void*)g,
      (__attribute__((address_space(3))) void*)l, 16, 0, 0);
}

// ---------------- hist + weight-prep (merged) ----------------
__global__ void hist_prep_k(const int* __restrict__ ei, int E, int N,
                            int* __restrict__ counts, int gE,
                            const float* __restrict__ W1, unsigned short* __restrict__ W1t,
                            const float* __restrict__ W2, unsigned short* __restrict__ W2t,
                            const float* __restrict__ ca, float* __restrict__ cn,
                            unsigned* __restrict__ red) {
  const int b = blockIdx.x;
  const int tid = threadIdx.x;
  if (b < gE) {
    int i = b * 256 + tid;
    int Eall = E + N;
    if (i >= Eall) return;
    int dst = (i < E) ? ei[E + i] : (i - E);
    atomicAdd(&counts[dst], 1);
  } else {
    int bb = b - gE;
    if (bb < 1024) {
      int i = bb * 256 + tid;
      int c = i >> 9, k = i & 511;
      W1t[i] = f2bf(W1[(size_t)k * 512 + c]);
    } else if (bb < 1024 + 128) {
      int i = (bb - 1024) * 256 + tid;
      int c = i >> 9, k = i & 511;
      W2t[i] = f2bf(W2[(size_t)k * 64 + c]);
    } else {
      int lane = tid & 63, c = tid >> 6;
      float v = ca[c * 64 + lane];
      float p = v * v;
#pragma unroll
      for (int o = 32; o; o >>= 1) p += __shfl_xor(p, o);
      cn[c * 64 + lane] = v / fmaxf(sqrtf(p), 1e-12f);
      if (tid == 0) { red[0] = 0u; red[1] = 0u; }
    }
  }
}

// ---------------- scan phase 1: per-256-chunk inclusive scan + chunk sums ----------------
__global__ __launch_bounds__(256) void scan1_k(const int* __restrict__ counts,
                                               int* __restrict__ incl,
                                               int* __restrict__ bsum, int N) {
  int b = blockIdx.x, tid = threadIdx.x;
  int lane = tid & 63, wv = tid >> 6;
  int i = b * 256 + tid;
  int v = (i < N) ? counts[i] : 0;
#pragma unroll
  for (int o = 1; o < 64; o <<= 1) {
    int t = __shfl_up(v, o, 64);
    if (lane >= o) v += t;
  }
  __shared__ int wsum[4];
  if (lane == 63) wsum[wv] = v;
  __syncthreads();
  int base = 0;
  for (int wj = 0; wj < wv; wj++) base += wsum[wj];
  v += base;
  if (i < N) incl[i] = v;
  if (tid == 255) bsum[b] = v;
}

// ---------------- scan phase 2 (inlined prefix) + emit offs/cursor ----------------
__global__ __launch_bounds__(256) void scan3_k(const int* __restrict__ incl,
                                               const int* __restrict__ bsum,
                                               int* __restrict__ offs,
                                               int* __restrict__ cursor, int N) {
  const int b = blockIdx.x, tid = threadIdx.x;
  __shared__ int s_pre;
  if (tid < 64) {
    int p = 0;
    for (int i = tid; i < b; i += 64) p += bsum[i];
#pragma unroll
    for (int o = 32; o; o >>= 1) p += __shfl_xor(p, o);
    if (tid == 0) s_pre = p;
  }
  __syncthreads();
  const int prefix = s_pre;
  int i = b * 256 + tid;
  if (i == 0) { offs[0] = 0; cursor[0] = 0; }
  if (i < N) {
    int v = incl[i] + prefix;
    offs[i + 1] = v;
    if (i + 1 < N) cursor[i + 1] = v;
  }
}

__global__ void scatter_k(const int* __restrict__ ei, int E, int N,
                          int* __restrict__ cursor, int* __restrict__ ssrc) {
  int i = blockIdx.x * 256 + threadIdx.x;
  int Eall = E + N;
  if (i >= Eall) return;
  int src, dst;
  if (i < E) { src = ei[i]; dst = ei[E + i]; }
  else       { src = i - E; dst = i - E; }
  int pos = atomicAdd(&cursor[dst], 1);
  ssrc[pos] = src;
}

// ---------------- GEMM1: h[M,512] = x_fp32[M,512] @ W1t^T, bf16 out, fused dots ----------------
// BM=128, BN=512 (single col-pass), BK=64; 1024 thr, 16 waves (2 row x 8 col),
// wave tile 64x64. grid (Mpad/128). A staged from fp32 (conv fused). LDS 88 KB.
__global__ __launch_bounds__(1024, 1) void gemm1_k(const float* __restrict__ X,
                                                   const unsigned short* __restrict__ Bt,
                                                   unsigned short* __restrict__ C,
                                                   const float* __restrict__ att_s,
                                                   const float* __restrict__ att_d,
                                                   float* __restrict__ as_out,
                                                   float* __restrict__ ad_out,
                                                   int M, int K, int Nc) {
  __shared__ unsigned short As[128][64];
  __shared__ unsigned short Bs[512][64];
  __shared__ float s_ds[8][128];
  __shared__ float s_dd[8][128];
  const int tid = threadIdx.x;
  const int lane = tid & 63;
  const int w = tid >> 6;          // 0..15
  const int wr = w >> 3, wc = w & 7;
  const int l16 = lane & 15, lk = lane >> 4;
  const int row0 = blockIdx.x * 128;

  f32x4 acc[4][4];
#pragma unroll
  for (int m = 0; m < 4; m++)
#pragma unroll
    for (int n = 0; n < 4; n++) acc[m][n] = (f32x4)0.f;

  const char* Bbase = (const char*)Bt;

  for (int k0 = 0; k0 < K; k0 += 64) {
#pragma unroll
    for (int i = 0; i < 4; i++) {
      int cb = i * 1024 + tid;
      int c = cb >> 3, b = (cb & 7) * 16;
      gll16(Bbase + ((size_t)c * K + k0) * 2 + b, (char*)&Bs[0][0] + cb * 16);
    }
    {
      int r = tid >> 3, c = (tid & 7) * 8;
      int row = row0 + r;
      if (row >= M) row = M - 1;
      const float* src = X + (size_t)row * K + k0 + c;
      float4 a0 = *(const float4*)src;
      float4 a1 = *(const float4*)(src + 4);
      u16x8 pk;
      pk[0] = f2bf(a0.x); pk[1] = f2bf(a0.y); pk[2] = f2bf(a0.z); pk[3] = f2bf(a0.w);
      pk[4] = f2bf(a1.x); pk[5] = f2bf(a1.y); pk[6] = f2bf(a1.z); pk[7] = f2bf(a1.w);
      *(u16x8*)&As[r][c] = pk;
    }
    __syncthreads();
#pragma unroll
    for (int ks = 0; ks < 2; ks++) {
      bf16x8 af[4], bfr[4];
#pragma unroll
      for (int m = 0; m < 4; m++)
        af[m] = *(const bf16x8*)&As[wr * 64 + m * 16 + l16][ks * 32 + lk * 8];
#pragma unroll
      for (int n = 0; n < 4; n++)
        bfr[n] = *(const bf16x8*)&Bs[wc * 64 + n * 16 + l16][ks * 32 + lk * 8];
#pragma unroll
      for (int m = 0; m < 4; m++)
#pragma unroll
        for (int n = 0; n < 4; n++)
          acc[m][n] = __builtin_amdgcn_mfma_f32_16x16x32_bf16(af[m], bfr[n], acc[m][n], 0, 0, 0);
    }
    __syncthreads();
  }
#pragma unroll
  for (int m = 0; m < 4; m++) {
    int row_b = row0 + wr * 64 + m * 16 + lk * 4;
#pragma unroll
    for (int r = 0; r < 4; r++) {
      int row = row_b + r;
      if (row < M) {
#pragma unroll
        for (int n = 0; n < 4; n++) {
          int col = wc * 64 + n * 16 + l16;
          C[(size_t)row * Nc + col] = f2bf(acc[m][n][r]);
        }
      }
    }
  }
  // fused dots: head = wc>>1 (two waves per head, combined in LDS)
  float as_c[4], ad_c[4];
#pragma unroll
  for (int n = 0; n < 4; n++) {
    int col = wc * 64 + n * 16 + l16;
    as_c[n] = att_s[col];
    ad_c[n] = att_d[col];
  }
#pragma unroll
  for (int m = 0; m < 4; m++) {
#pragma unroll
    for (int r = 0; r < 4; r++) {
      float ps = 0.f, pd = 0.f;
#pragma unroll
      for (int n = 0; n < 4; n++) {
        ps += acc[m][n][r] * as_c[n];
        pd += acc[m][n][r] * ad_c[n];
      }
#pragma unroll
      for (int o = 8; o; o >>= 1) { ps += __shfl_xor(ps, o); pd += __shfl_xor(pd, o); }
      if (l16 == 0) {
        int rr = wr * 64 + m * 16 + lk * 4 + r;
        s_ds[wc][rr] = ps;
        s_dd[wc][rr] = pd;
      }
    }
  }
  __syncthreads();
  if (tid < 128) {
    int row = row0 + tid;
    if (row < M) {
#pragma unroll
      for (int h = 0; h < 4; h++) {
        as_out[(size_t)row * 4 + h] = s_ds[2 * h][tid] + s_ds[2 * h + 1][tid];
        ad_out[(size_t)row * 4 + h] = s_dd[2 * h][tid] + s_dd[2 * h + 1][tid];
      }
    }
  }
}

// ---------------- GEMM2: h2pre[M,64] = h1b[M,512] @ W2t^T, bf16 out, fused dots ----------------
__global__ __launch_bounds__(256) void gemm2_k(const unsigned short* __restrict__ A,
                                               const unsigned short* __restrict__ Bt,
                                               unsigned short* __restrict__ C,
                                               const float* __restrict__ att_s,
                                               const float* __restrict__ att_d,
                                               float* __restrict__ as_out,
                                               float* __restrict__ ad_out,
                                               int M, int K, int Nc) {
  __shared__ unsigned short As[64][64];
  __shared__ unsigned short Bs[64][64];
  __shared__ float s_ds[2][64];
  __shared__ float s_dd[2][64];
  const int tid = threadIdx.x;
  const int lane = tid & 63;
  const int w = tid >> 6;
  const int wr = w >> 1, wc = w & 1;
  const int l16 = lane & 15, lk = lane >> 4;
  const int row0 = blockIdx.x * 64;

  f32x4 acc[2][2];
#pragma unroll
  for (int m = 0; m < 2; m++)
#pragma unroll
    for (int n = 0; n < 2; n++) acc[m][n] = (f32x4)0.f;

  const char* Abase = (const char*)A;
  const char* Bbase = (const char*)Bt;

  for (int k0 = 0; k0 < K; k0 += 64) {
#pragma unroll
    for (int i = 0; i < 2; i++) {
      int ca = i * 256 + tid;
      int r = ca >> 3, b = (ca & 7) * 16;
      gll16(Abase + ((size_t)(row0 + r) * K + k0) * 2 + b, (char*)&As[0][0] + ca * 16);
    }
#pragma unroll
    for (int i = 0; i < 2; i++) {
      int cb = i * 256 + tid;
      int c = cb >> 3, b = (cb & 7) * 16;
      gll16(Bbase + ((size_t)c * K + k0) * 2 + b, (char*)&Bs[0][0] + cb * 16);
    }
    __syncthreads();
#pragma unroll
    for (int ks = 0; ks < 2; ks++) {
      bf16x8 af[2], bfr[2];
#pragma unroll
      for (int m = 0; m < 2; m++)
        af[m] = *(const bf16x8*)&As[wr * 32 + m * 16 + l16][ks * 32 + lk * 8];
#pragma unroll
      for (int n = 0; n < 2; n++)
        bfr[n] = *(const bf16x8*)&Bs[wc * 32 + n * 16 + l16][ks * 32 + lk * 8];
#pragma unroll
      for (int m = 0; m < 2; m++)
#pragma unroll
        for (int n = 0; n < 2; n++)
          acc[m][n] = __builtin_amdgcn_mfma_f32_16x16x32_bf16(af[m], bfr[n], acc[m][n], 0, 0, 0);
    }
    __syncthreads();
  }
#pragma unroll
  for (int m = 0; m < 2; m++) {
    int row_b = row0 + wr * 32 + m * 16 + lk * 4;
#pragma unroll
    for (int r = 0; r < 4; r++) {
      int row = row_b + r;
      if (row < M) {
#pragma unroll
        for (int n = 0; n < 2; n++) {
          int col = wc * 32 + n * 16 + l16;
          C[(size_t)row * Nc + col] = f2bf(acc[m][n][r]);
        }
      }
    }
  }
  float as_c[2], ad_c[2];
#pragma unroll
  for (int n = 0; n < 2; n++) {
    int col = wc * 32 + n * 16 + l16;
    as_c[n] = att_s[col];
    ad_c[n] = att_d[col];
  }
#pragma unroll
  for (int m = 0; m < 2; m++) {
#pragma unroll
    for (int r = 0; r < 4; r++) {
      float ps = 0.f, pd = 0.f;
#pragma unroll
      for (int n = 0; n < 2; n++) {
        ps += acc[m][n][r] * as_c[n];
        pd += acc[m][n][r] * ad_c[n];
      }
#pragma unroll
      for (int o = 8; o; o >>= 1) { ps += __shfl_xor(ps, o); pd += __shfl_xor(pd, o); }
      if (l16 == 0) {
        int rr = wr * 32 + m * 16 + lk * 4 + r;
        s_ds[wc][rr] = ps;
        s_dd[wc][rr] = pd;
      }
    }
  }
  __syncthreads();
  if (tid < 64) {
    int row = row0 + tid;
    if (row < M) {
      as_out[row] = s_ds[0][tid] + s_ds[1][tid];
      ad_out[row] = s_dd[0][tid] + s_dd[1][tid];
    }
  }
}

// ---------------- GAT layer 1 aggregation: wave per dst node, barrier-free ----------------
__global__ __launch_bounds__(256) void gat_agg1_k(const unsigned short* __restrict__ hfeat,
                                                  const float* __restrict__ a_s,
                                                  const float* __restrict__ a_d,
                                                  const int* __restrict__ offs,
                                                  const int* __restrict__ ssrc,
                                                  const float* __restrict__ b1,
                                                  unsigned short* __restrict__ h1b, int N) {
  const int tid = threadIdx.x;
  const int lane = tid & 63, wave = tid >> 6;
  const int n = blockIdx.x * 4 + wave;
  if (n >= N) return;
  __shared__ int   s_src[4][64];
  __shared__ float s_ex[4][64][4];
  const int start = offs[n], end = offs[n + 1];
  const int hhl = lane >> 4;
  const float4 adv4 = *(const float4*)(a_d + (size_t)n * 4);
  const float4* as4 = (const float4*)a_s;

  float m0 = -1e30f, m1 = -1e30f, m2 = -1e30f, m3 = -1e30f;
  float S0 = 0.f, S1 = 0.f, S2 = 0.f, S3 = 0.f;
  float acc[8] = {0.f, 0.f, 0.f, 0.f, 0.f, 0.f, 0.f, 0.f};

  for (int base = start; base < end; base += 64) {
    const int cnt = min(64, end - base);
    float e0 = -1e30f, e1 = -1e30f, e2 = -1e30f, e3 = -1e30f;
    int s = 0;
    if (lane < cnt) {
      s = ssrc[base + lane];
      float4 av = as4[s];
      e0 = lrelu02(av.x + adv4.x);
      e1 = lrelu02(av.y + adv4.y);
      e2 = lrelu02(av.z + adv4.z);
      e3 = lrelu02(av.w + adv4.w);
    }
    float c0 = e0, c1 = e1, c2 = e2, c3 = e3;
#pragma unroll
    for (int o = 32; o; o >>= 1) {
      c0 = fmaxf(c0, __shfl_xor(c0, o));
      c1 = fmaxf(c1, __shfl_xor(c1, o));
      c2 = fmaxf(c2, __shfl_xor(c2, o));
      c3 = fmaxf(c3, __shfl_xor(c3, o));
    }
    float nm0 = fmaxf(m0, c0), nm1 = fmaxf(m1, c1);
    float nm2 = fmaxf(m2, c2), nm3 = fmaxf(m3, c3);
    float sc0 = __expf(m0 - nm0), sc1 = __expf(m1 - nm1);
    float sc2 = __expf(m2 - nm2), sc3 = __expf(m3 - nm3);
    m0 = nm0; m1 = nm1; m2 = nm2; m3 = nm3;
    float x0 = (lane < cnt) ? __expf(e0 - nm0) : 0.f;
    float x1 = (lane < cnt) ? __expf(e1 - nm1) : 0.f;
    float x2 = (lane < cnt) ? __expf(e2 - nm2) : 0.f;
    float x3 = (lane < cnt) ? __expf(e3 - nm3) : 0.f;
    s_src[wave][lane] = s;
    s_ex[wave][lane][0] = x0; s_ex[wave][lane][1] = x1;
    s_ex[wave][lane][2] = x2; s_ex[wave][lane][3] = x3;
#pragma unroll
    for (int o = 32; o; o >>= 1) {
      x0 += __shfl_xor(x0, o); x1 += __shfl_xor(x1, o);
      x2 += __shfl_xor(x2, o); x3 += __shfl_xor(x3, o);
    }
    S0 = S0 * sc0 + x0; S1 = S1 * sc1 + x1;
    S2 = S2 * sc2 + x2; S3 = S3 * sc3 + x3;
    float scl = (hhl == 0) ? sc0 : (hhl == 1) ? sc1 : (hhl == 2) ? sc2 : sc3;
#pragma unroll
    for (int q = 0; q < 8; q++) acc[q] *= scl;
#pragma unroll 4
    for (int j = 0; j < cnt; j++) {
      int sj = s_src[wave][j];
      float al = s_ex[wave][j][hhl];
      uint4 pk = *(const uint4*)(hfeat + ((size_t)sj << 9) + lane * 8);
      acc[0] += al * __uint_as_float(pk.x << 16);
      acc[1] += al * __uint_as_float(pk.x & 0xFFFF0000u);
      acc[2] += al * __uint_as_float(pk.y << 16);
      acc[3] += al * __uint_as_float(pk.y & 0xFFFF0000u);
      acc[4] += al * __uint_as_float(pk.z << 16);
      acc[5] += al * __uint_as_float(pk.z & 0xFFFF0000u);
      acc[6] += al * __uint_as_float(pk.w << 16);
      acc[7] += al * __uint_as_float(pk.w & 0xFFFF0000u);
    }
  }
  float inv = 1.f / (((hhl == 0) ? S0 : (hhl == 1) ? S1 : (hhl == 2) ? S2 : S3) + 1e-16f);
  const float4 b1a = *(const float4*)(b1 + lane * 8);
  const float4 b1b = *(const float4*)(b1 + lane * 8 + 4);
  float v[8];
  v[0] = acc[0] * inv + b1a.x; v[1] = acc[1] * inv + b1a.y;
  v[2] = acc[2] * inv + b1a.z; v[3] = acc[3] * inv + b1a.w;
  v[4] = acc[4] * inv + b1b.x; v[5] = acc[5] * inv + b1b.y;
  v[6] = acc[6] * inv + b1b.z; v[7] = acc[7] * inv + b1b.w;
  u16x8 outv;
#pragma unroll
  for (int q = 0; q < 8; q++) {
    float t = v[q] > 0.f ? v[q] : (__expf(v[q]) - 1.f);
    outv[q] = f2bf(t);
  }
  __builtin_nontemporal_store(outv, (u16x8*)(h1b + ((size_t)n << 9) + lane * 8));
}

// ---------------- GAT layer 2 aggregation + fused intra-attention score ----------------
__global__ __launch_bounds__(256) void gat_agg2_k(const unsigned short* __restrict__ h2b,
                                                  const float* __restrict__ a_s,
                                                  const float* __restrict__ a_d,
                                                  const int* __restrict__ offs,
                                                  const int* __restrict__ ssrc,
                                                  const float* __restrict__ b2,
                                                  const float* __restrict__ Wa,
                                                  const float* __restrict__ ba,
                                                  const float* __restrict__ wv,
                                                  const float* __restrict__ bv,
                                                  float* __restrict__ h2out,
                                                  float* __restrict__ scores, int N) {
  const int tid = threadIdx.x;
  const int lane = tid & 63, wave = tid >> 6;
  const int n = blockIdx.x * 4 + wave;
  if (n >= N) return;
  __shared__ int   s_src[4][64];
  __shared__ float s_ex[4][64];
  const int start = offs[n], end = offs[n + 1];
  const float ad = a_d[n];
  const int half = lane >> 5, l32 = lane & 31;

  float m = -1e30f, S = 0.f, acc0 = 0.f, acc1 = 0.f;
  for (int base = start; base < end; base += 64) {
    const int cnt = min(64, end - base);
    float e = -1e30f;
    int s = 0;
    if (lane < cnt) {
      s = ssrc[base + lane];
      e = lrelu02(a_s[s] + ad);
    }
    float c = e;
#pragma unroll
    for (int o = 32; o; o >>= 1) c = fmaxf(c, __shfl_xor(c, o));
    float nm = fmaxf(m, c);
    float sc = __expf(m - nm);
    m = nm;
    float x = (lane < cnt) ? __expf(e - nm) : 0.f;
    s_src[wave][lane] = s;
    s_ex[wave][lane] = x;
    float xs = x;
#pragma unroll
    for (int o = 32; o; o >>= 1) xs += __shfl_xor(xs, o);
    S = S * sc + xs;
    acc0 *= sc; acc1 *= sc;
#pragma unroll 8
    for (int j = half; j < cnt; j += 2) {
      int sj = s_src[wave][j];
      float al = s_ex[wave][j];
      unsigned pk = *(const unsigned*)(h2b + ((size_t)sj << 6) + l32 * 2);
      acc0 += al * __uint_as_float(pk << 16);
      acc1 += al * __uint_as_float(pk & 0xFFFF0000u);
    }
  }
  acc0 += __shfl_xor(acc0, 32);
  acc1 += __shfl_xor(acc1, 32);
  float inv = 1.f / (S + 1e-16f);
  float hx = acc0 * inv + b2[l32 * 2];
  float hy = acc1 * inv + b2[l32 * 2 + 1];
  if (half == 0) {
    float2 o;
    o.x = hx; o.y = hy;
    *(float2*)(h2out + ((size_t)n << 6) + l32 * 2) = o;
  }
  // fused score: t[lane] = ba[lane] + sum_k h2[k]*Wa[k][lane]
  float t = ba[lane];
#pragma unroll 8
  for (int k = 0; k < 32; k++) {
    float a = __shfl(hx, k);
    float b = __shfl(hy, k);
    t += a * Wa[(2 * k) * 64 + lane] + b * Wa[(2 * k + 1) * 64 + lane];
  }
  t = tanhf(t);
  float p = t * wv[lane];
#pragma unroll
  for (int o = 32; o; o >>= 1) p += __shfl_xor(p, o);
  if (lane == 0) scores[n] = p + bv[0];
}

// ---------------- global exp-sum: full-block reduce, ONE atomic per block ----------------
__global__ __launch_bounds__(256) void score_sum_k(const float* __restrict__ scores,
                                                   unsigned* __restrict__ red, int N) {
  __shared__ float s_w[4];
  int tid = threadIdx.x;
  int i = blockIdx.x * 256 + tid;
  // scores are tanh-bounded (|s| <~ 3): no max-shift needed
  float s = (i < N) ? __expf(scores[i]) : 0.f;
#pragma unroll
  for (int o = 32; o; o >>= 1) s += __shfl_xor(s, o);
  if ((tid & 63) == 0) s_w[tid >> 6] = s;
  __syncthreads();
  if (tid == 0)
    atomicAdd(reinterpret_cast<float*>(red) + 1, s_w[0] + s_w[1] + s_w[2] + s_w[3]);
}

__global__ __launch_bounds__(256) void finalize_k(const float* __restrict__ h2,
                                                  const float* __restrict__ scores,
                                                  const unsigned* __restrict__ red,
                                                  const float* __restrict__ cn,
                                                  const float* __restrict__ Wc,
                                                  const float* __restrict__ bc,
                                                  float* __restrict__ out, int N) {
  int lane = threadIdx.x & 63, wave = threadIdx.x >> 6;
  int n = blockIdx.x * 4 + wave;
  if (n >= N) return;
  float S = __uint_as_float(red[1]);
  float attw = __expf(scores[n]) / S;
  float xw = h2[(size_t)n * 64 + lane] * attw;
  float p = xw * xw;
#pragma unroll
  for (int o = 32; o; o >>= 1) p += __shfl_xor(p, o);
  float xn = xw / fmaxf(sqrtf(p), 1e-12f);
  float i0 = xn * cn[lane],       i1 = xn * cn[64 + lane];
  float i2 = xn * cn[128 + lane], i3 = xn * cn[192 + lane];
  float o0 = xw * Wc[lane * 4 + 0], o1 = xw * Wc[lane * 4 + 1];
  float o2 = xw * Wc[lane * 4 + 2], o3 = xw * Wc[lane * 4 + 3];
#pragma unroll
  for (int o = 32; o; o >>= 1) {
    i0 += __shfl_xor(i0, o); i1 += __shfl_xor(i1, o);
    i2 += __shfl_xor(i2, o); i3 += __shfl_xor(i3, o);
    o0 += __shfl_xor(o0, o); o1 += __shfl_xor(o1, o);
    o2 += __shfl_xor(o2, o); o3 += __shfl_xor(o3, o);
  }
  float* outp   = out;
  float* xwp    = out + (size_t)N * 4;
  float* interp = out + (size_t)N * 68;
  xwp[(size_t)n * 64 + lane] = xw;
  if (lane == 0) {
    outp[n * 4 + 0] = o0 + bc[0]; outp[n * 4 + 1] = o1 + bc[1];
    outp[n * 4 + 2] = o2 + bc[2]; outp[n * 4 + 3] = o3 + bc[3];
    interp[n * 4 + 0] = i0; interp[n * 4 + 1] = i1;
    interp[n * 4 + 2] = i2; interp[n * 4 + 3] = i3;
  }
}

// ---------------- launch ----------------
extern "C" void kernel_launch(void* const* d_in, const int* in_sizes, int n_in,
                              void* d_out, int out_size, void* d_ws, size_t ws_size,
                              hipStream_t stream) {
  const float* x        = (const float*)d_in[0];
  const int*   ei       = (const int*)d_in[1];
  const float* W1       = (const float*)d_in[2];
  const float* att_src1 = (const float*)d_in[3];
  const float* att_dst1 = (const float*)d_in[4];
  const float* b1       = (const float*)d_in[5];
  const float* W2       = (const float*)d_in[6];
  const float* att_src2 = (const float*)d_in[7];
  const float* att_dst2 = (const float*)d_in[8];
  const float* b2       = (const float*)d_in[9];
  const float* Wa       = (const float*)d_in[10];
  const float* ba       = (const float*)d_in[11];
  const float* wv       = (const float*)d_in[12];
  const float* bv       = (const float*)d_in[13];
  const float* class_attn = (const float*)d_in[14];
  const float* Wc       = (const float*)d_in[15];
  const float* bc       = (const float*)d_in[16];

  const int N = in_sizes[0] / 512;
  const int E = in_sizes[1] / 2;
  const int Eall = E + N;
  const int Mpad = ((N + 127) / 128) * 128;
  const int nb = (N + 255) / 256;

  char* w = (char*)d_ws;
  size_t off = 0;
  auto alloc = [&](size_t bytes) -> void* {
    off = (off + 255) & ~((size_t)255);
    void* p = w + off;
    off += bytes;
    return p;
  };
  unsigned short* h1b = (unsigned short*)alloc((size_t)Mpad * 512 * 2);
  unsigned short* hb  = (unsigned short*)alloc((size_t)N * 512 * 2);     // h = x@W1, bf16
  unsigned short* h2b = (unsigned short*)alloc((size_t)N * 64 * 2);      // h2pre bf16
  float* h2     = (float*)alloc((size_t)N * 64 * 4);
  unsigned short* W1t = (unsigned short*)alloc((size_t)512 * 512 * 2);
  unsigned short* W2t = (unsigned short*)alloc((size_t)64 * 512 * 2);
  float* as1    = (float*)alloc((size_t)N * 4 * 4);
  float* ad1    = (float*)alloc((size_t)N * 4 * 4);
  float* as2    = (float*)alloc((size_t)N * 4);
  float* ad2    = (float*)alloc((size_t)N * 4);
  int*   counts = (int*)alloc((size_t)N * 4);
  int*   incl   = (int*)alloc((size_t)N * 4);
  int*   bsum   = (int*)alloc(256 * 4);
  int*   offs   = (int*)alloc((size_t)(N + 1) * 4);
  int*   cursor = (int*)alloc((size_t)N * 4);
  int*   ssrc   = (int*)alloc((size_t)Eall * 4);
  float* scores = (float*)alloc((size_t)N * 4);
  unsigned* red = (unsigned*)alloc(64);
  float* cn     = (float*)alloc(256 * 4);

  const int gN256  = (N + 255) / 256;
  const int gE256  = (Eall + 255) / 256;
  const int gNode4 = (N + 3) / 4;

  // --- CSR build + weight prep ---
  hipMemsetAsync(counts, 0, (size_t)N * 4, stream);
  hist_prep_k<<<gE256 + 1024 + 128 + 1, 256, 0, stream>>>(
      ei, E, N, counts, gE256, W1, W1t, W2, W2t, class_attn, cn, red);
  scan1_k<<<nb, 256, 0, stream>>>(counts, incl, bsum, N);
  scan3_k<<<gN256, 256, 0, stream>>>(incl, bsum, offs, cursor, N);
  scatter_k<<<gE256, 256, 0, stream>>>(ei, E, N, cursor, ssrc);

  // --- layer 1 ---
  gemm1_k<<<Mpad / 128, 1024, 0, stream>>>(
      x, W1t, hb, att_src1, att_dst1, as1, ad1, N, 512, 512);
  gat_agg1_k<<<gNode4, 256, 0, stream>>>(hb, as1, ad1, offs, ssrc, b1, h1b, N);

  // --- layer 2 ---
  gemm2_k<<<dim3(Mpad / 64, 1), 256, 0, stream>>>(
      h1b, W2t, h2b, att_src2, att_dst2, as2, ad2, N, 512, 64);
  gat_agg2_k<<<gNode4, 256, 0, stream>>>(h2b, as2, ad2, offs, ssrc, b2,
                                         Wa, ba, wv, bv, h2, scores, N);

  // --- global softmax + finalize ---
  score_sum_k<<<gN256, 256, 0, stream>>>(scores, red, N);
  finalize_k<<<gNode4, 256, 0, stream>>>(h2, scores, red, cn, Wc, bc,
                                         (float*)d_out, N);
}